// Round 4
// baseline (4786.246 us; speedup 1.0000x reference)
//
#include <hip/hip_runtime.h>

#define NS   16384
#define NIN  16384
#define CIN  128
#define COUT 128
#define KNB  9
#define MCH  66              // 64 MLP channels + 1 (b3 ones) + 1 zero pad
#define QDIM (CIN*MCH)       // 8448, q = m*128 + j (j-fastest)
#define W0C  30.0f

typedef __bf16 bf16;
typedef bf16  bf16x8  __attribute__((ext_vector_type(8)));
typedef float floatx4 __attribute__((ext_vector_type(4)));
typedef unsigned int u32;

__device__ inline unsigned short f2bf(float f){
  u32 u = __float_as_uint(f);
  u += 0x7fffu + ((u >> 16) & 1u);   // round-to-nearest-even
  return (unsigned short)(u >> 16);
}
__device__ inline u32 pack2bf(float lo, float hi){
  return (u32)f2bf(lo) | ((u32)f2bf(hi) << 16);
}
__device__ inline float bf2f(unsigned short s){
  return __uint_as_float((u32)s << 16);
}

// ---------------- K0: Vt[i][q] bf16, q = m*128+j ----------------
__global__ void k0_vt(const float* __restrict__ W3, const float* __restrict__ b3,
                      unsigned short* __restrict__ Vt){
  int idx = blockIdx.x*256 + threadIdx.x;
  if (idx >= COUT*QDIM) return;
  int i = idx / QDIM;
  int q = idx - i*QDIM;
  int m = q >> 7;
  int j = q & 127;
  float v = 0.f;
  if (m < 64)       v = W3[m*16384 + i*128 + j];
  else if (m == 64) v = b3[i*128 + j];
  Vt[idx] = f2bf(v);
}

// ---------------- K1: SIREN MLP (fp32 math, bf16 out), h[pt][66] ----------------
__global__ __launch_bounds__(256) void k1_mlp(const float* __restrict__ coords,
      const float* __restrict__ W1, const float* __restrict__ b1,
      const float* __restrict__ W2, const float* __restrict__ b2,
      unsigned short* __restrict__ h){
  int lane = threadIdx.x & 63;
  int pt = blockIdx.x*4 + (threadIdx.x >> 6);
  float c0 = coords[2*pt], c1 = coords[2*pt+1];
  float z  = fmaf(c0, W1[lane], fmaf(c1, W1[64+lane], b1[lane]));
  float h1 = sinf(W0C * z);
  float acc = b2[lane];
  #pragma unroll
  for (int mp = 0; mp < 64; ++mp)
    acc = fmaf(__shfl(h1, mp, 64), W2[mp*64 + lane], acc);
  float h2 = sinf(acc);
  size_t base = (size_t)pt * MCH;
  h[base + lane] = f2bf(h2);
  if (lane == 0){ h[base+64] = 0x3F80; h[base+65] = 0; }  // 1.0, 0.0
}

// ---------------- K1t: transpose h[pt][66] -> hT[m][pt] ----------------
__global__ __launch_bounds__(256) void k1t(const unsigned short* __restrict__ h,
                                           unsigned short* __restrict__ hT){
  __shared__ unsigned short t[128][68];
  int pt0 = blockIdx.x*128;
  int tid = threadIdx.x;
  for (int e = tid; e < 128*MCH; e += 256){
    int p = e / MCH, m = e - p*MCH;
    t[p][m] = h[(size_t)(pt0 + p)*MCH + m];
  }
  __syncthreads();
  for (int e = tid; e < MCH*128; e += 256){
    int m = e >> 7, p = e & 127;
    hT[(size_t)m*(KNB*NS) + pt0 + p] = t[p][m];
  }
}

// ---------------- K_tr: transpose x[b][j][p] -> xT[b][p][j] (bf16) ----------------
__global__ void k_tr(const float* __restrict__ x, unsigned short* __restrict__ xT){
  __shared__ __align__(16) float t[32][33];
  int b  = blockIdx.z;
  int j0 = blockIdx.y*32;
  int p0 = blockIdx.x*32;
  int tx = threadIdx.x, ty = threadIdx.y;
  const float*    xb  = x  + (size_t)b*CIN*NIN;
  unsigned short* xTb = xT + (size_t)b*NIN*CIN;
  #pragma unroll
  for (int n = 0; n < 4; ++n)
    t[ty+8*n][tx] = xb[(size_t)(j0+ty+8*n)*NIN + p0+tx];
  __syncthreads();
  #pragma unroll
  for (int n = 0; n < 4; ++n)
    xTb[(size_t)(p0+ty+8*n)*CIN + j0+tx] = f2bf(t[tx][ty+8*n]);
}

// ---------------- K_fused: build A-slabs on the fly + MFMA GEMM ----------------
// block: 128 rows (one b, 128 l's) x 128 i, 512 threads.
__global__ __launch_bounds__(512, 4) void k_fused(
      const unsigned short* __restrict__ xT,   // [4][16384][128] bf16
      const unsigned short* __restrict__ hT,   // [66][9*16384]  bf16
      const int* __restrict__ nb,              // [9][16384]
      const unsigned short* __restrict__ Vt,   // [128][8448]    bf16
      const float* __restrict__ bias,
      float* __restrict__ out){
  __shared__ __align__(16) unsigned short A[2][128][136];  // 69,632 B (row stride 272 B)
  __shared__ unsigned short hm[2][KNB][128];               //  4,608 B
  __shared__ int pk[KNB][128];                             //  4,608 B

  const int tid = threadIdx.x;
  const int r0  = blockIdx.x * 128;
  const int b   = r0 >> 14;
  const int l0  = r0 & (NS-1);

  for (int e = tid; e < KNB*128; e += 512){
    int k = e >> 7, l = e & 127;
    pk[k][l] = nb[k*NS + l0 + l];
  }
  __syncthreads();

  // build-phase identity: thread owns (l = tid>>2, j0 = (tid&3)*32)
  const int lq = tid >> 2;
  const int jh = tid & 3;
  const char* xbB = (const char*)(xT + ((size_t)b << 21));
  u32 xoff[KNB];
  #pragma unroll
  for (int k = 0; k < KNB; ++k)
    xoff[k] = ((u32)pk[k][lq] << 8) + (u32)jh*64;   // byte offset of 64-B segment

  // mfma-phase identity
  const int lane  = tid & 63;
  const int w     = tid >> 6;
  const int ar    = lane & 15;
  const int klane = lane >> 4;
  const int wr = (w & 3) * 32;    // l-offset within block tile
  const int wc = (w >> 2) * 64;   // i-offset

  floatx4 acc[2][4];
  #pragma unroll
  for (int fr = 0; fr < 2; ++fr)
    #pragma unroll
    for (int fc = 0; fc < 4; ++fc) acc[fr][fc] = (floatx4){0.f,0.f,0.f,0.f};

  for (int mg = 0; mg < 33; ++mg){
    // stage h-pair (also acts as the A-reuse barrier)
    for (int e = tid; e < 2*KNB*128; e += 512){
      int mm = e / (KNB*128);
      int rkl = e - mm*(KNB*128);
      int k = rkl >> 7, l = rkl & 127;
      hm[mm][k][l] = hT[(size_t)(mg*2 + mm)*(KNB*NS) + ((size_t)k << 14) + l0 + l];
    }
    __syncthreads();   // hm ready; prev mfma A-reads complete -> safe to rebuild A

    // ---- build A[2][128 l][128 j] for this m-pair ----
    float a0[32], a1[32];
    #pragma unroll
    for (int t = 0; t < 32; ++t){ a0[t] = 0.f; a1[t] = 0.f; }
    #pragma unroll
    for (int k = 0; k < KNB; ++k){
      const bf16x8* xp = (const bf16x8*)(xbB + xoff[k]);
      bf16x8 xv0 = xp[0], xv1 = xp[1], xv2 = xp[2], xv3 = xp[3];
      float hk0 = bf2f(hm[0][k][lq]);
      float hk1 = bf2f(hm[1][k][lq]);
      #pragma unroll
      for (int t = 0; t < 8; ++t){
        float f0 = (float)xv0[t], f1 = (float)xv1[t], f2 = (float)xv2[t], f3 = (float)xv3[t];
        a0[t]    = fmaf(hk0, f0, a0[t]);    a1[t]    = fmaf(hk1, f0, a1[t]);
        a0[t+8]  = fmaf(hk0, f1, a0[t+8]);  a1[t+8]  = fmaf(hk1, f1, a1[t+8]);
        a0[t+16] = fmaf(hk0, f2, a0[t+16]); a1[t+16] = fmaf(hk1, f2, a1[t+16]);
        a0[t+24] = fmaf(hk0, f3, a0[t+24]); a1[t+24] = fmaf(hk1, f3, a1[t+24]);
      }
    }
    {
      u32* d0 = (u32*)&A[0][lq][0] + jh*16;
      u32* d1 = (u32*)&A[1][lq][0] + jh*16;
      #pragma unroll
      for (int t = 0; t < 16; ++t) d0[t] = pack2bf(a0[2*t], a0[2*t+1]);
      #pragma unroll
      for (int t = 0; t < 16; ++t) d1[t] = pack2bf(a1[2*t], a1[2*t+1]);
    }
    __syncthreads();   // A ready

    // ---- MFMA: 2 m-slabs x 4 K-iters of 32 ----
    #pragma unroll
    for (int mm = 0; mm < 2; ++mm){
      const char* Ab = (const char*)&A[mm][0][0];
      const size_t vbyte = (size_t)((mg*2 + mm)*128)*2 + (size_t)klane*16;
      #pragma unroll
      for (int kt = 0; kt < 4; ++kt){
        bf16x8 av[2], bv[4];
        #pragma unroll
        for (int fr = 0; fr < 2; ++fr)
          av[fr] = *(const bf16x8*)(Ab + (wr + fr*16 + ar)*272 + kt*64 + klane*16);
        #pragma unroll
        for (int fc = 0; fc < 4; ++fc)
          bv[fc] = *(const bf16x8*)((const char*)Vt +
                    (size_t)(wc + fc*16 + ar)*(QDIM*2) + vbyte + kt*64);
        #pragma unroll
        for (int fr = 0; fr < 2; ++fr)
          #pragma unroll
          for (int fc = 0; fc < 4; ++fc)
            acc[fr][fc] = __builtin_amdgcn_mfma_f32_16x16x32_bf16(av[fr], bv[fc], acc[fr][fc], 0, 0, 0);
      }
    }
    __syncthreads();   // mfma A-reads done before next group's rebuild
  }

  // ---- epilogue: plain stores + bias ----
  float* ob = out + ((size_t)b << 21);
  #pragma unroll
  for (int fc = 0; fc < 4; ++fc){
    int i = wc + fc*16 + ar;
    float bi = bias[i];
    #pragma unroll
    for (int fr = 0; fr < 2; ++fr){
      int l = l0 + wr + fr*16 + klane*4;
      float4 v;
      v.x = acc[fr][fc][0] + bi;
      v.y = acc[fr][fc][1] + bi;
      v.z = acc[fr][fc][2] + bi;
      v.w = acc[fr][fc][3] + bi;
      *(float4*)(ob + ((size_t)i << 14) + l) = v;
    }
  }
}

// ---------------- Naive zero-workspace fallback (correctness net) ----------------
__global__ __launch_bounds__(256) void k_naive(const float* __restrict__ x,
      const int* __restrict__ nb, const float* __restrict__ coords,
      const float* __restrict__ W1, const float* __restrict__ b1,
      const float* __restrict__ W2, const float* __restrict__ b2,
      const float* __restrict__ W3, const float* __restrict__ b3,
      const float* __restrict__ bias, float* __restrict__ out){
  __shared__ __align__(16) float hk[KNB][68];
  __shared__ int pk[KNB];
  __shared__ __align__(16) float xg[4][KNB][128];
  __shared__ __align__(16) float ul[128][66];
  int tid = threadIdx.x;
  int l = blockIdx.x;
  int lane = tid & 63, wid = tid >> 6;
  if (tid < KNB) pk[tid] = nb[tid*NS + l];
  for (int k = wid; k < KNB; k += 4){
    int pt = k*NS + l;
    float c0 = coords[2*pt], c1 = coords[2*pt+1];
    float z  = fmaf(c0, W1[lane], fmaf(c1, W1[64+lane], b1[lane]));
    float h1 = sinf(W0C*z);
    float a = b2[lane];
    for (int mp = 0; mp < 64; ++mp)
      a = fmaf(__shfl(h1, mp, 64), W2[mp*64+lane], a);
    hk[k][lane] = sinf(a);
    if (lane == 0){ hk[k][64] = 1.f; hk[k][65] = 0.f; }
  }
  __syncthreads();
  for (int idx = tid; idx < 4*KNB*128; idx += 256){
    int b = idx / (KNB*128);
    int r = idx - b*KNB*128;
    int k = r >> 7;
    int j = r & 127;
    xg[b][k][j] = x[((size_t)b*CIN + j)*NIN + pk[k]];
  }
  __syncthreads();
  for (int b = 0; b < 4; ++b){
    for (int idx = tid; idx < 128*65; idx += 256){
      int j = idx / 65, m = idx - j*65;
      float s = 0.f;
      for (int k = 0; k < KNB; ++k) s = fmaf(xg[b][k][j], hk[k][m], s);
      ul[j][m] = s;
    }
    __syncthreads();
    if (tid < 128){
      int i = tid;
      float v = bias[i];
      for (int j = 0; j < 128; ++j){
        const float* wcol = W3 + i*128 + j;
        for (int m = 0; m < 64; ++m)
          v = fmaf(ul[j][m], wcol[(size_t)m*16384], v);
        v = fmaf(ul[j][64], b3[i*128+j], v);
      }
      out[((size_t)b<<21) + ((size_t)i<<14) + l] = v;
    }
    __syncthreads();
  }
}

extern "C" void kernel_launch(void* const* d_in, const int* in_sizes, int n_in,
                              void* d_out, int out_size, void* d_ws, size_t ws_size,
                              hipStream_t stream) {
  const float* x      = (const float*)d_in[0];
  const int*   nb     = (const int*)  d_in[1];
  const float* coords = (const float*)d_in[2];
  const float* W1     = (const float*)d_in[3];
  const float* b1     = (const float*)d_in[4];
  const float* W2     = (const float*)d_in[5];
  const float* b2     = (const float*)d_in[6];
  const float* W3     = (const float*)d_in[7];
  const float* b3     = (const float*)d_in[8];
  const float* bias   = (const float*)d_in[9];
  float* out = (float*)d_out;

  const size_t VT_BYTES = (size_t)COUT*QDIM*2;            //  2,162,688
  const size_t H_BYTES  = (size_t)KNB*NS*MCH*2;           // 19,464,192
  const size_t HT_BYTES = (size_t)MCH*KNB*NS*2;           // 19,464,192
  const size_t XT_BYTES = (size_t)4*NIN*CIN*2;            // 16,777,216
  const size_t FIXED    = VT_BYTES + H_BYTES + HT_BYTES + XT_BYTES;  // ~57.9 MB

  if (ws_size >= FIXED) {
    char* ws = (char*)d_ws;
    unsigned short* Vt = (unsigned short*)ws;
    unsigned short* h  = (unsigned short*)(ws + VT_BYTES);
    unsigned short* hT = (unsigned short*)(ws + VT_BYTES + H_BYTES);
    unsigned short* xT = (unsigned short*)(ws + VT_BYTES + H_BYTES + HT_BYTES);

    k0_vt<<<(COUT*QDIM + 255)/256, 256, 0, stream>>>(W3, b3, Vt);
    k1_mlp<<<(KNB*NS)/4, 256, 0, stream>>>(coords, W1, b1, W2, b2, h);
    k1t<<<(KNB*NS)/128, 256, 0, stream>>>(h, hT);
    k_tr<<<dim3(NIN/32, CIN/32, 4), dim3(32, 8), 0, stream>>>(x, xT);
    k_fused<<<(4*NS)/128, 512, 0, stream>>>(xT, hT, nb, Vt, bias, out);
  } else {
    k_naive<<<NS, 256, 0, stream>>>(x, nb, coords, W1, b1, W2, b2, W3, b3, bias, out);
  }
  (void)in_sizes; (void)n_in; (void)out_size;
}

// Round 5
// 735.012 us; speedup vs baseline: 6.5118x; 6.5118x over previous
//
#include <hip/hip_runtime.h>

#define NS   16384
#define NIN  16384
#define CIN  128
#define COUT 128
#define KNB  9
#define MCH  66              // 64 MLP channels + 1 (b3 ones) + 1 zero pad
#define QDIM (CIN*MCH)       // 8448, q = m*128 + j (j-fastest)
#define W0C  30.0f

typedef __bf16 bf16;
typedef bf16  bf16x8  __attribute__((ext_vector_type(8)));
typedef float floatx4 __attribute__((ext_vector_type(4)));
typedef unsigned int u32;

__device__ inline unsigned short f2bf(float f){
  u32 u = __float_as_uint(f);
  u += 0x7fffu + ((u >> 16) & 1u);   // round-to-nearest-even
  return (unsigned short)(u >> 16);
}
__device__ inline u32 pack2bf(float lo, float hi){
  return (u32)f2bf(lo) | ((u32)f2bf(hi) << 16);
}
__device__ inline float bf2f(unsigned short s){
  return __uint_as_float((u32)s << 16);
}

// ---------------- K0: Vt[i][q] bf16, q = m*128+j ----------------
__global__ void k0_vt(const float* __restrict__ W3, const float* __restrict__ b3,
                      unsigned short* __restrict__ Vt){
  int idx = blockIdx.x*256 + threadIdx.x;
  if (idx >= COUT*QDIM) return;
  int i = idx / QDIM;
  int q = idx - i*QDIM;
  int m = q >> 7;
  int j = q & 127;
  float v = 0.f;
  if (m < 64)       v = W3[m*16384 + i*128 + j];
  else if (m == 64) v = b3[i*128 + j];
  Vt[idx] = f2bf(v);
}

// ---------------- K1: SIREN MLP (fp32 math, bf16 out), h[pt][66] ----------------
__global__ __launch_bounds__(256) void k1_mlp(const float* __restrict__ coords,
      const float* __restrict__ W1, const float* __restrict__ b1,
      const float* __restrict__ W2, const float* __restrict__ b2,
      unsigned short* __restrict__ h){
  int lane = threadIdx.x & 63;
  int pt = blockIdx.x*4 + (threadIdx.x >> 6);
  float c0 = coords[2*pt], c1 = coords[2*pt+1];
  float z  = fmaf(c0, W1[lane], fmaf(c1, W1[64+lane], b1[lane]));
  float h1 = sinf(W0C * z);
  float acc = b2[lane];
  #pragma unroll
  for (int mp = 0; mp < 64; ++mp)
    acc = fmaf(__shfl(h1, mp, 64), W2[mp*64 + lane], acc);
  float h2 = sinf(acc);
  size_t base = (size_t)pt * MCH;
  h[base + lane] = f2bf(h2);
  if (lane == 0){ h[base+64] = 0x3F80; h[base+65] = 0; }  // 1.0, 0.0
}

// ---------------- K1tp: h[pt][66] -> hTp[g][pt] u32 (m-pair packed) ----------------
__global__ __launch_bounds__(256) void k1tp(const unsigned short* __restrict__ h,
                                            u32* __restrict__ hTp){
  __shared__ unsigned short t[128][68];
  int pt0 = blockIdx.x*128;
  int tid = threadIdx.x;
  for (int e = tid; e < 128*MCH; e += 256){
    int p = e / MCH, m = e - p*MCH;
    t[p][m] = h[(size_t)(pt0 + p)*MCH + m];
  }
  __syncthreads();
  for (int e = tid; e < 33*128; e += 256){
    int g = e >> 7, p = e & 127;
    hTp[(size_t)g*(KNB*NS) + pt0 + p] = (u32)t[p][2*g] | ((u32)t[p][2*g+1] << 16);
  }
}

// ---------------- K_tr: transpose x[b][j][p] -> xT[b][p][j] (bf16) ----------------
__global__ void k_tr(const float* __restrict__ x, unsigned short* __restrict__ xT){
  __shared__ __align__(16) float t[32][33];
  int b  = blockIdx.z;
  int j0 = blockIdx.y*32;
  int p0 = blockIdx.x*32;
  int tx = threadIdx.x, ty = threadIdx.y;
  const float*    xb  = x  + (size_t)b*CIN*NIN;
  unsigned short* xTb = xT + (size_t)b*NIN*CIN;
  #pragma unroll
  for (int n = 0; n < 4; ++n)
    t[ty+8*n][tx] = xb[(size_t)(j0+ty+8*n)*NIN + p0+tx];
  __syncthreads();
  #pragma unroll
  for (int n = 0; n < 4; ++n)
    xTb[(size_t)(p0+ty+8*n)*CIN + j0+tx] = f2bf(t[tx][ty+8*n]);
}

// ---------------- K_fused: register-resident gather + on-the-fly A + MFMA ----------
// block: 32 rows (one b) x 128 i, 512 threads (8 waves).
// thread build identity: l = tid>>4, j-chunk = (tid&15)*8  (x-hat: 36 VGPR, loaded ONCE)
// wave w: col-frag i0 = w*16; row-frags rf in {0,1}.
__global__ __launch_bounds__(512, 4) void k_fused(
      const unsigned short* __restrict__ xT,   // [4][16384][128] bf16
      const u32* __restrict__ hTp,             // [33][9*16384]   u32 (m-pair)
      const int* __restrict__ nb,              // [9][16384]
      const unsigned short* __restrict__ Vt,   // [128][8448]     bf16
      const float* __restrict__ bias,
      float* __restrict__ out){
  __shared__ __align__(16) unsigned short A[2][32][136];  // 17,408 B (row 272 B)
  __shared__ u32 hm2[KNB][32];                            //  1,152 B
  __shared__ int pk[KNB][32];                             //  1,152 B

  const int tid = threadIdx.x;
  const int r0  = blockIdx.x * 32;
  const int b   = r0 >> 14;
  const int l0  = r0 & (NS-1);

  if (tid < KNB*32){
    int k = tid >> 5, l = tid & 31;
    pk[k][l] = nb[k*NS + l0 + l];
  }
  __syncthreads();

  const int lq = tid >> 4;      // 0..31
  const int jc = tid & 15;      // j = jc*8
  const char* xbB = (const char*)(xT + ((size_t)b << 21));
  bf16x8 xk[KNB];
  #pragma unroll
  for (int k = 0; k < KNB; ++k)
    xk[k] = *(const bf16x8*)(xbB + (((size_t)(u32)pk[k][lq]) << 8) + (size_t)jc*16);

  const int lane  = tid & 63;
  const int w     = tid >> 6;   // i0 = w*16
  const int ar    = lane & 15;
  const int klane = lane >> 4;

  floatx4 acc[2];
  acc[0] = (floatx4){0.f,0.f,0.f,0.f};
  acc[1] = (floatx4){0.f,0.f,0.f,0.f};

  const char* VtB = (const char*)Vt + (size_t)(w*16 + ar)*(QDIM*2) + (size_t)klane*16;

  for (int mg = 0; mg < 33; ++mg){
    // stage packed h-pair (runs while previous iteration's MFMA still reads A)
    if (tid < KNB*32){
      int k = tid >> 5, l = tid & 31;
      hm2[k][l] = hTp[(size_t)mg*(KNB*NS) + ((size_t)k << 14) + l0 + l];
    }
    __syncthreads();   // hm2 ready AND prev MFMA A-reads drained

    // ---- build: a2[j] = { sum_k x*h_m0 , sum_k x*h_m1 } ----
    float a2x[8], a2y[8];
    #pragma unroll
    for (int t = 0; t < 8; ++t){ a2x[t] = 0.f; a2y[t] = 0.f; }
    #pragma unroll
    for (int k = 0; k < KNB; ++k){
      u32 hw = hm2[k][lq];                       // 16-lane broadcast
      float hk0 = bf2f((unsigned short)(hw & 0xffff));
      float hk1 = bf2f((unsigned short)(hw >> 16));
      #pragma unroll
      for (int t = 0; t < 8; ++t){
        float xf = (float)xk[k][t];
        a2x[t] = fmaf(xf, hk0, a2x[t]);
        a2y[t] = fmaf(xf, hk1, a2y[t]);
      }
    }
    {
      u32 p0[4], p1[4];
      #pragma unroll
      for (int t = 0; t < 4; ++t){
        p0[t] = pack2bf(a2x[2*t], a2x[2*t+1]);
        p1[t] = pack2bf(a2y[2*t], a2y[2*t+1]);
      }
      *(uint4*)&A[0][lq][jc*8] = *(uint4*)p0;
      *(uint4*)&A[1][lq][jc*8] = *(uint4*)p1;
    }
    __syncthreads();   // A ready

    // ---- MFMA: 2 m-slabs x 4 K-iters of 32, B straight from L2-hot Vt ----
    #pragma unroll
    for (int mm = 0; mm < 2; ++mm){
      const char* Ab = (const char*)&A[mm][0][0] + (size_t)klane*16;
      const char* Vg = VtB + (size_t)((mg*2 + mm)*128)*2;
      #pragma unroll
      for (int kt = 0; kt < 4; ++kt){
        bf16x8 bv = *(const bf16x8*)(Vg + kt*64);
        bf16x8 av0 = *(const bf16x8*)(Ab + (0*16 + ar)*272 + kt*64);
        bf16x8 av1 = *(const bf16x8*)(Ab + (1*16 + ar)*272 + kt*64);
        acc[0] = __builtin_amdgcn_mfma_f32_16x16x32_bf16(av0, bv, acc[0], 0, 0, 0);
        acc[1] = __builtin_amdgcn_mfma_f32_16x16x32_bf16(av1, bv, acc[1], 0, 0, 0);
      }
    }
    __syncthreads();   // MFMA A-reads done before next rebuild
  }

  // ---- epilogue ----
  float* ob = out + ((size_t)b << 21);
  int i = w*16 + ar;
  float bi = bias[i];
  #pragma unroll
  for (int rf = 0; rf < 2; ++rf){
    int l = l0 + rf*16 + klane*4;
    float4 v;
    v.x = acc[rf][0] + bi;
    v.y = acc[rf][1] + bi;
    v.z = acc[rf][2] + bi;
    v.w = acc[rf][3] + bi;
    *(float4*)(ob + ((size_t)i << 14) + l) = v;
  }
}

// ---------------- Naive zero-workspace fallback (correctness net) ----------------
__global__ __launch_bounds__(256) void k_naive(const float* __restrict__ x,
      const int* __restrict__ nb, const float* __restrict__ coords,
      const float* __restrict__ W1, const float* __restrict__ b1,
      const float* __restrict__ W2, const float* __restrict__ b2,
      const float* __restrict__ W3, const float* __restrict__ b3,
      const float* __restrict__ bias, float* __restrict__ out){
  __shared__ __align__(16) float hk[KNB][68];
  __shared__ int pk[KNB];
  __shared__ __align__(16) float xg[4][KNB][128];
  __shared__ __align__(16) float ul[128][66];
  int tid = threadIdx.x;
  int l = blockIdx.x;
  int lane = tid & 63, wid = tid >> 6;
  if (tid < KNB) pk[tid] = nb[tid*NS + l];
  for (int k = wid; k < KNB; k += 4){
    int pt = k*NS + l;
    float c0 = coords[2*pt], c1 = coords[2*pt+1];
    float z  = fmaf(c0, W1[lane], fmaf(c1, W1[64+lane], b1[lane]));
    float h1 = sinf(W0C*z);
    float a = b2[lane];
    for (int mp = 0; mp < 64; ++mp)
      a = fmaf(__shfl(h1, mp, 64), W2[mp*64+lane], a);
    hk[k][lane] = sinf(a);
    if (lane == 0){ hk[k][64] = 1.f; hk[k][65] = 0.f; }
  }
  __syncthreads();
  for (int idx = tid; idx < 4*KNB*128; idx += 256){
    int b = idx / (KNB*128);
    int r = idx - b*KNB*128;
    int k = r >> 7;
    int j = r & 127;
    xg[b][k][j] = x[((size_t)b*CIN + j)*NIN + pk[k]];
  }
  __syncthreads();
  for (int b = 0; b < 4; ++b){
    for (int idx = tid; idx < 128*65; idx += 256){
      int j = idx / 65, m = idx - j*65;
      float s = 0.f;
      for (int k = 0; k < KNB; ++k) s = fmaf(xg[b][k][j], hk[k][m], s);
      ul[j][m] = s;
    }
    __syncthreads();
    if (tid < 128){
      int i = tid;
      float v = bias[i];
      for (int j = 0; j < 128; ++j){
        const float* wcol = W3 + i*128 + j;
        for (int m = 0; m < 64; ++m)
          v = fmaf(ul[j][m], wcol[(size_t)m*16384], v);
        v = fmaf(ul[j][64], b3[i*128+j], v);
      }
      out[((size_t)b<<21) + ((size_t)i<<14) + l] = v;
    }
    __syncthreads();
  }
}

extern "C" void kernel_launch(void* const* d_in, const int* in_sizes, int n_in,
                              void* d_out, int out_size, void* d_ws, size_t ws_size,
                              hipStream_t stream) {
  const float* x      = (const float*)d_in[0];
  const int*   nb     = (const int*)  d_in[1];
  const float* coords = (const float*)d_in[2];
  const float* W1     = (const float*)d_in[3];
  const float* b1     = (const float*)d_in[4];
  const float* W2     = (const float*)d_in[5];
  const float* b2     = (const float*)d_in[6];
  const float* W3     = (const float*)d_in[7];
  const float* b3     = (const float*)d_in[8];
  const float* bias   = (const float*)d_in[9];
  float* out = (float*)d_out;

  const size_t VT_BYTES = (size_t)COUT*QDIM*2;            //  2,162,688
  const size_t H_BYTES  = (size_t)KNB*NS*MCH*2;           // 19,464,192
  const size_t HT_BYTES = (size_t)33*KNB*NS*4;            // 19,464,192
  const size_t XT_BYTES = (size_t)4*NIN*CIN*2;            // 16,777,216
  const size_t FIXED    = VT_BYTES + H_BYTES + HT_BYTES + XT_BYTES;  // ~57.9 MB

  if (ws_size >= FIXED) {
    char* ws = (char*)d_ws;
    unsigned short* Vt = (unsigned short*)ws;
    unsigned short* h  = (unsigned short*)(ws + VT_BYTES);
    u32*            hTp= (u32*)(ws + VT_BYTES + H_BYTES);
    unsigned short* xT = (unsigned short*)(ws + VT_BYTES + H_BYTES + HT_BYTES);

    k0_vt<<<(COUT*QDIM + 255)/256, 256, 0, stream>>>(W3, b3, Vt);
    k1_mlp<<<(KNB*NS)/4, 256, 0, stream>>>(coords, W1, b1, W2, b2, h);
    k1tp<<<(KNB*NS)/128, 256, 0, stream>>>(h, hTp);
    k_tr<<<dim3(NIN/32, CIN/32, 4), dim3(32, 8), 0, stream>>>(x, xT);
    k_fused<<<(4*NS)/32, 512, 0, stream>>>(xT, hTp, nb, Vt, bias, out);
  } else {
    k_naive<<<NS, 256, 0, stream>>>(x, nb, coords, W1, b1, W2, b2, W3, b3, bias, out);
  }
  (void)in_sizes; (void)n_in; (void)out_size;
}